// Round 6
// baseline (2986.931 us; speedup 1.0000x reference)
//
#include <hip/hip_runtime.h>
#include <hip/hip_cooperative_groups.h>

namespace cg = cooperative_groups;

// ---------------------------------------------------------------------------
// SparsePoolingLayer: u0 = conv5x5_valid(x, W_ff); iterate
//   u <- 0.5*u + 0.5*(u0 - W_rec @ a); a = relu(u - thr)
// until ||u_new - u||/||u_new|| < 1e-3 (device-checked), max 41 iterations.
//
// R14 design: persistent cooperative iteration, FL layout, reg-resident u.
//  - R13 confirmed FL layout removed the L2 thrash (pairs < 150 us), but the
//    iter phase is still ~700 us: ~5 pairs x ~130 us (3x over the 49 us
//    traffic+compute roofline, latency/launch-bound) + ~15 stub launches +
//    final_out.
//  - R14: 450 blocks x 512 threads (2/CU co-resident), 4 tiles/block.
//    u state = sv[4][4] int4 packed fp16 = 64 VGPRs, statically indexed.
//    GEMM in j-halves (acc[2][2]=16 regs, single bfr) -> peak live ~120
//    < 128 cap of launch_bounds(512,4). R9's spill was 260 regs at cap 256;
//    this is the same idea with 2.3x less state.
//  - Per iteration: read u0 (59 MB, LLC-resident) only; no state writes.
//    One grid.sync + 16-slot norms -> exact first-crossing; out written
//    directly from regs at the end (fuses final_out).
//  - Numerics chain identical to R13 (same fp16 rounding, rec fp32).
//  - Fallback: full R13 multi-launch pair path if cooperative launch fails.
// ---------------------------------------------------------------------------

typedef __attribute__((ext_vector_type(8))) short short8;
typedef __attribute__((ext_vector_type(4))) float f32x4;

#define NTOT 115200   // 32*60*60
#define CHW  262144   // 64*64*64
#define HW2  4096     // 64*64
#define LDA  264      // a_lds row stride in shorts (528 B)
#define LDC  40       // conv LDS row stride in shorts (80 B, 16B-aligned rows)

__device__ __forceinline__ unsigned short f2bf(float f) {
  unsigned int u = __float_as_uint(f);
  unsigned int r = u + 0x7FFFu + ((u >> 16) & 1u);
  return (unsigned short)(r >> 16);
}
__device__ __forceinline__ float bf2f(unsigned short h) {
  return __uint_as_float(((unsigned int)h) << 16);
}
__device__ __forceinline__ unsigned short f2h(float f) {
  _Float16 x = (_Float16)f;
  unsigned short r;
  __builtin_memcpy(&r, &x, 2);
  return r;
}
__device__ __forceinline__ float h2f(unsigned short h) {
  _Float16 x;
  __builtin_memcpy(&x, &h, 2);
  return (float)x;
}

// ---------------------------------------------------------------------------
// Weight prep:
//  wff[o][(ky*5+kx)*64+ci] bf16  (conv A operand rows)
//  wrec_sw: per-lane MFMA fragment order: for 8-wide ic-chunk cc (0..31),
//  oc row o: wrec_sw[((cc*256)+o)*8 + j] = W_rec[o][cc*8+j]
__global__ void cast_weights(const float* __restrict__ wff_f,
                             const float* __restrict__ wrec_f,
                             unsigned short* __restrict__ wff,
                             unsigned short* __restrict__ wrec_sw) {
  int tid = blockIdx.x * 256 + threadIdx.x;
  if (tid < 409600) {
    int o = tid / 1600, k = tid % 1600;
    int kk = k >> 6, ci = k & 63;            // k = kk*64 + ci
    wff[tid] = f2bf(wff_f[o * 1600 + ci * 25 + kk]);
  } else if (tid < 409600 + 65536) {
    int i = tid - 409600;
    int o = i >> 8, ic = i & 255;
    wrec_sw[(((ic >> 3) << 8) + o) * 8 + (ic & 7)] = f2bf(wrec_f[i]);
  }
}

// ---------------------------------------------------------------------------
// x NCHW fp32 -> NHWC bf16: xt[(b*4096 + y*64 + x)*64 + ci].
__global__ __launch_bounds__(256) void transpose_x(
    const float* __restrict__ x, unsigned short* __restrict__ xt) {
  int g = blockIdx.x * 256 + threadIdx.x;          // 131072 = 32*4096
  const float* src = x + (long)(g >> 12) * CHW + (g & 4095);
  unsigned short* dst = xt + (long)g * 64;
#pragma unroll
  for (int oct = 0; oct < 8; ++oct) {
    alignas(16) unsigned short tmp[8];
#pragma unroll
    for (int d = 0; d < 8; ++d)
      tmp[d] = f2bf(src[(oct * 8 + d) * HW2]);
    *(int4*)(dst + oct * 8) = *(const int4*)tmp;
  }
}

// ---------------------------------------------------------------------------
// Conv as implicit GEMM, D[oc][n] (A = wff, B = x). Block 128oc x 128n,
// BK=32, grid (900, 2). Writes u0 fp16 in FL layout (coalesced int4).
__global__ __launch_bounds__(256) void conv_kernel(
    const unsigned short* __restrict__ xt,
    const unsigned short* __restrict__ wff,
    unsigned short* __restrict__ u0_fl) {
  __shared__ short As[128 * LDC];  // x-tile  [n][k]  pad 32->40
  __shared__ short Bs[128 * LDC];  // wff     [oc][k]
  const int t = threadIdx.x;
  const int n0 = blockIdx.x * 128;
  const int oc0 = blockIdx.y * 128;
  const int lane = t & 63, w = t >> 6;
  const int q = lane >> 4, r = lane & 15;
  const int woc = w >> 1, wn = w & 1;      // oc-half, n-half
  const int qt = t & 3, mrow = t >> 2;     // staging: row mrow(+64), 16B qt

  int xbase[2];
#pragma unroll
  for (int p = 0; p < 2; ++p) {
    int n = n0 + p * 64 + mrow;
    int bb = n / 3600, rem = n - bb * 3600;
    int yy = rem / 60, xx = rem - yy * 60;
    xbase[p] = (bb * 4096 + yy * 64 + xx) * 64 + qt * 8;
  }

  f32x4 acc[4][4];
#pragma unroll
  for (int i = 0; i < 4; i++)
#pragma unroll
    for (int j = 0; j < 4; j++) acc[i][j] = (f32x4){0.f, 0.f, 0.f, 0.f};

  for (int c = 0; c < 50; ++c) {
    const int k0 = c * 32;
    const int kk = c >> 1;                 // ky*5+kx, uniform per chunk
    const int ky = kk / 5, kx = kk - ky * 5;
    const int choff = (ky * 64 + kx) * 64 + (c & 1) * 32;  // scalar-uniform

    __syncthreads();
#pragma unroll
    for (int p = 0; p < 2; ++p) {          // wff: 128 oc-rows x 32 k
      int m = p * 64 + mrow;
      *(int4*)(&Bs[m * LDC + qt * 8]) =
          *(const int4*)(wff + (oc0 + m) * 1600 + k0 + qt * 8);
    }
#pragma unroll
    for (int p = 0; p < 2; ++p) {          // x-tile: contiguous bf16 (NHWC)
      int m = p * 64 + mrow;
      *(int4*)(&As[m * LDC + qt * 8]) = *(const int4*)(xt + xbase[p] + choff);
    }
    __syncthreads();

    short8 xf[4], wf[4];
#pragma unroll
    for (int j = 0; j < 4; j++)
      xf[j] = *(const short8*)(&As[(wn * 64 + j * 16 + r) * LDC + q * 8]);
#pragma unroll
    for (int i = 0; i < 4; i++)
      wf[i] = *(const short8*)(&Bs[(woc * 64 + i * 16 + r) * LDC + q * 8]);
#pragma unroll
    for (int i = 0; i < 4; i++)
#pragma unroll
      for (int j = 0; j < 4; j++)
        acc[i][j] = __builtin_amdgcn_mfma_f32_16x16x32_bf16(wf[i], xf[j],
                                                            acc[i][j], 0, 0, 0);
  }

  // epilogue: FL layout. Store addr = tile*16384 + j*4096 +
  // (w_fl*64 + q*16 + r)*8 : lane-contiguous -> 512 B/instr coalesced.
  const int tile = blockIdx.x * 2 + wn;
#pragma unroll
  for (int j = 0; j < 4; j++) {
#pragma unroll
    for (int p = 0; p < 2; p++) {
      const int w_fl = blockIdx.y * 4 + woc * 2 + p;
      alignas(16) unsigned short up[8];
#pragma unroll
      for (int d = 0; d < 4; ++d) up[d] = f2h(acc[2 * p][j][d]);
#pragma unroll
      for (int d = 0; d < 4; ++d) up[4 + d] = f2h(acc[2 * p + 1][j][d]);
      *(int4*)(&u0_fl[tile * 16384 + j * 4096 + (w_fl * 64 + q * 16 + r) * 8]) =
          *(const int4*)up;
    }
  }
}

// ---------------------------------------------------------------------------
// R14: persistent cooperative iteration kernel. 450 blocks x 512 threads,
// 4 tiles/block; sv[4][4] int4 fp16 = reg-resident u. Per iteration per
// tile: stage a -> barrier -> 2 j-half GEMMs (acc[2][2], single bfr) with
// u0 loads issued at half start -> in-reg update -> barrier. Then block
// reduce + 16-slot atomics + grid.sync + uniform first-crossing decision.
// On exit, out (NCHW fp32) written directly from regs.
__global__ __launch_bounds__(512, 4) void iter_persist(
    const unsigned short* __restrict__ wrec_sw,
    const unsigned short* __restrict__ u0,
    const float* __restrict__ thr,
    float* __restrict__ norms,
    float* __restrict__ out) {
  __shared__ short a_lds[64 * LDA];
  __shared__ float red[16];

  const int t = threadIdx.x;
  const int lane = t & 63, w = t >> 6;     // w in 0..7
  const int q = lane >> 4, r = lane & 15;

  float thc[2][4];
#pragma unroll
  for (int i = 0; i < 2; ++i) {
    float4 th = *(const float4*)(thr + w * 32 + i * 16 + q * 4);
    thc[i][0] = th.x; thc[i][1] = th.y; thc[i][2] = th.z; thc[i][3] = th.w;
  }

  cg::grid_group grid = cg::this_grid();

  int4 sv[4][4];                           // [tile][j], 64 VGPRs
#pragma unroll
  for (int tt = 0; tt < 4; ++tt) {
    const unsigned base = (blockIdx.x * 4 + tt) * 16384 + t * 8;
#pragma unroll
    for (int j = 0; j < 4; ++j)
      sv[tt][j] = *(const int4*)(u0 + base + j * 4096);
  }

  int it = 1;
  for (;; ++it) {
    float d2 = 0.f, n2 = 0.f;
#pragma unroll
    for (int tt = 0; tt < 4; ++tt) {
      const unsigned base = (blockIdx.x * 4 + tt) * 16384 + t * 8;
      // ---- stage a = relu(sv - thr) -> LDS (bf16) ----
#pragma unroll
      for (int j = 0; j < 4; ++j) {
        const unsigned short* hs = (const unsigned short*)&sv[tt][j];
#pragma unroll
        for (int i = 0; i < 2; ++i) {
          alignas(8) unsigned short ap[4];
#pragma unroll
          for (int d = 0; d < 4; ++d) {
            float a = h2f(hs[i * 4 + d]) - thc[i][d];
            ap[d] = f2bf(a > 0.f ? a : 0.f);
          }
          *(uint2*)(&a_lds[(j * 16 + r) * LDA + w * 32 + i * 16 + q * 4]) =
              *(const uint2*)ap;
        }
      }
      __syncthreads();

      // ---- two j-halves: GEMM (acc[2][2]) + in-reg update ----
#pragma unroll
      for (int h = 0; h < 2; ++h) {
        int4 u0h[2];
#pragma unroll
        for (int jj = 0; jj < 2; ++jj)     // issue early; complete under GEMM
          u0h[jj] = *(const int4*)(u0 + base + (h * 2 + jj) * 4096);

        f32x4 acc[2][2];
#pragma unroll
        for (int i = 0; i < 2; i++)
#pragma unroll
          for (int jj = 0; jj < 2; jj++) acc[i][jj] = (f32x4){0.f, 0.f, 0.f, 0.f};
#pragma unroll
        for (int c = 0; c < 8; ++c) {
          short8 afr[2];
#pragma unroll
          for (int i = 0; i < 2; i++)
            afr[i] = *(const short8*)(wrec_sw +
                     (((c * 4 + q) << 8) + w * 32 + i * 16 + r) * 8);
#pragma unroll
          for (int jj = 0; jj < 2; ++jj) {
            short8 bfr = *(const short8*)(
                &a_lds[((h * 2 + jj) * 16 + r) * LDA + c * 32 + q * 8]);
#pragma unroll
            for (int i = 0; i < 2; i++)
              acc[i][jj] = __builtin_amdgcn_mfma_f32_16x16x32_bf16(
                  afr[i], bfr, acc[i][jj], 0, 0, 0);
          }
        }

#pragma unroll
        for (int jj = 0; jj < 2; ++jj) {
          const int j = h * 2 + jj;
          const unsigned short* us = (const unsigned short*)&u0h[jj];
          const unsigned short* hs = (const unsigned short*)&sv[tt][j];
          alignas(16) unsigned short up[8];
#pragma unroll
          for (int i = 0; i < 2; ++i)
#pragma unroll
            for (int d = 0; d < 4; ++d) {
              float uo = (it == 1) ? 0.f : h2f(hs[i * 4 + d]);
              float un = 0.5f * uo +
                         0.5f * (h2f(us[i * 4 + d]) - acc[i][jj][d]);
              float df = un - uo;
              d2 += df * df;
              n2 += un * un;
              up[i * 4 + d] = f2h(un);
            }
          sv[tt][j] = *(const int4*)up;
        }
      }
      __syncthreads();                     // a_lds reused by next tile
    }

    // ---- reduce: wave -> block -> 8-slot atomics ----
#pragma unroll
    for (int off = 32; off; off >>= 1) {
      d2 += __shfl_down(d2, off, 64);
      n2 += __shfl_down(n2, off, 64);
    }
    if (lane == 0) { red[w] = d2; red[8 + w] = n2; }
    __syncthreads();
    if (t == 0) {
      float a0 = 0.f, a1 = 0.f;
#pragma unroll
      for (int s = 0; s < 8; ++s) { a0 += red[s]; a1 += red[8 + s]; }
      const int slot = blockIdx.x & 7;
      atomicAdd(&norms[it * 16 + slot], a0);
      atomicAdd(&norms[it * 16 + 8 + slot], a1);
    }
    grid.sync();
    float ds = 0.f, ns = 0.f;
#pragma unroll
    for (int s = 0; s < 8; ++s) {
      ds += __hip_atomic_load(&norms[it * 16 + s], __ATOMIC_RELAXED,
                              __HIP_MEMORY_SCOPE_AGENT);
      ns += __hip_atomic_load(&norms[it * 16 + 8 + s], __ATOMIC_RELAXED,
                              __HIP_MEMORY_SCOPE_AGENT);
    }
    if (ds < 1e-6f * ns || it == 41) break;  // uniform across grid
  }

  // ---- epilogue: out(NCHW fp32) = relu(sv - thr), scatter ----
#pragma unroll
  for (int tt = 0; tt < 4; ++tt) {
    const int tile = blockIdx.x * 4 + tt;
#pragma unroll
    for (int j = 0; j < 4; ++j) {
      const int n = tile * 64 + j * 16 + r;
      const int b = n / 3600, s = n - b * 3600;
      float* ob = out + (long)b * 921600 + s;
      const unsigned short* hs = (const unsigned short*)&sv[tt][j];
#pragma unroll
      for (int i = 0; i < 2; ++i)
#pragma unroll
        for (int d = 0; d < 4; ++d) {
          const int oc = w * 32 + i * 16 + q * 4 + d;
          float v = h2f(hs[i * 4 + d]) - thc[i][d];
          ob[oc * 3600] = v > 0.f ? v : 0.f;
        }
    }
  }
}

// ---------------------------------------------------------------------------
// Fallback path below (R13, proven at 1075 us): pair kernels + sel + final.
// ---------------------------------------------------------------------------
__device__ __forceinline__ void gemm_acc8(const short* a_lds,
                                          const unsigned short* __restrict__
                                              wrec_sw,
                                          int w, int q, int r,
                                          f32x4 acc[2][4]) {
#pragma unroll
  for (int i = 0; i < 2; i++)
#pragma unroll
    for (int j = 0; j < 4; j++) acc[i][j] = (f32x4){0.f, 0.f, 0.f, 0.f};

#pragma unroll
  for (int c = 0; c < 8; ++c) {
    short8 afr[2], bfr[4];
#pragma unroll
    for (int i = 0; i < 2; i++)
      afr[i] = *(const short8*)(wrec_sw +
               (((c * 4 + q) << 8) + w * 32 + i * 16 + r) * 8);
#pragma unroll
    for (int j = 0; j < 4; j++)
      bfr[j] = *(const short8*)(&a_lds[(j * 16 + r) * LDA + c * 32 + q * 8]);
#pragma unroll
    for (int i = 0; i < 2; i++)
#pragma unroll
      for (int j = 0; j < 4; j++)
        acc[i][j] = __builtin_amdgcn_mfma_f32_16x16x32_bf16(afr[i], bfr[j],
                                                            acc[i][j], 0, 0, 0);
  }
}

template <int FIRST>
__global__ __launch_bounds__(512, 4) void iter_pair(
    const unsigned short* __restrict__ wrec_sw,
    const unsigned short* __restrict__ u0, const float* __restrict__ thr,
    const unsigned short* __restrict__ uin,
    unsigned short* __restrict__ uA, unsigned short* __restrict__ uB,
    float* __restrict__ norms, int* __restrict__ flag, int itA) {
  __shared__ short a_lds[64 * LDA];
  __shared__ float red[32];

  const int t = threadIdx.x;
  if (!FIRST) {
    if (*(volatile int*)flag) return;
    float dA = 0.f, nA = 0.f, dB = 0.f, nB = 0.f;
#pragma unroll
    for (int s = 0; s < 8; ++s) {
      dA += norms[(itA - 2) * 16 + s];
      nA += norms[(itA - 2) * 16 + 8 + s];
      dB += norms[(itA - 1) * 16 + s];
      nB += norms[(itA - 1) * 16 + 8 + s];
    }
    if (dA < 1e-6f * nA || dB < 1e-6f * nB) {
      if (t == 0) *flag = 1;
      return;
    }
  }

  const int lane = t & 63, w = t >> 6;
  const int q = lane >> 4, r = lane & 15;
  const unsigned base = blockIdx.x * 16384 + t * 8;

  float thc[2][4];
#pragma unroll
  for (int i = 0; i < 2; ++i) {
    float4 th = *(const float4*)(thr + w * 32 + i * 16 + q * 4);
    thc[i][0] = th.x; thc[i][1] = th.y; thc[i][2] = th.z; thc[i][3] = th.w;
  }

  int4 sv[4], u0c[4];
#pragma unroll
  for (int j = 0; j < 4; ++j) {
    u0c[j] = *(const int4*)(u0 + base + j * 4096);
    sv[j] = FIRST ? u0c[j] : *(const int4*)(uin + base + j * 4096);
  }

#pragma unroll
  for (int j = 0; j < 4; ++j) {
    const unsigned short* hs = (const unsigned short*)&sv[j];
#pragma unroll
    for (int i = 0; i < 2; ++i) {
      alignas(8) unsigned short ap[4];
#pragma unroll
      for (int d = 0; d < 4; ++d) {
        float a = h2f(hs[i * 4 + d]) - thc[i][d];
        ap[d] = f2bf(a > 0.f ? a : 0.f);
      }
      *(uint2*)(&a_lds[(j * 16 + r) * LDA + w * 32 + i * 16 + q * 4]) =
          *(const uint2*)ap;
    }
  }
  __syncthreads();

  f32x4 acc[2][4];
  gemm_acc8(a_lds, wrec_sw, w, q, r, acc);

  float d2A = 0.f, n2A = 0.f;
#pragma unroll
  for (int j = 0; j < 4; ++j) {
    const unsigned short* us = (const unsigned short*)&u0c[j];
    const unsigned short* hs = (const unsigned short*)&sv[j];
    alignas(16) unsigned short up[8];
#pragma unroll
    for (int i = 0; i < 2; ++i)
#pragma unroll
      for (int d = 0; d < 4; ++d) {
        float uo = FIRST ? 0.f : h2f(hs[i * 4 + d]);
        float un = 0.5f * uo + 0.5f * (h2f(us[i * 4 + d]) - acc[i][j][d]);
        float df = un - uo;
        d2A += df * df;
        n2A += un * un;
        up[i * 4 + d] = f2h(un);
      }
    sv[j] = *(const int4*)up;
    *(int4*)(uA + base + j * 4096) = sv[j];
  }
  __syncthreads();

#pragma unroll
  for (int j = 0; j < 4; ++j) {
    const unsigned short* hs = (const unsigned short*)&sv[j];
#pragma unroll
    for (int i = 0; i < 2; ++i) {
      alignas(8) unsigned short ap[4];
#pragma unroll
      for (int d = 0; d < 4; ++d) {
        float a = h2f(hs[i * 4 + d]) - thc[i][d];
        ap[d] = f2bf(a > 0.f ? a : 0.f);
      }
      *(uint2*)(&a_lds[(j * 16 + r) * LDA + w * 32 + i * 16 + q * 4]) =
          *(const uint2*)ap;
    }
  }
  __syncthreads();

  gemm_acc8(a_lds, wrec_sw, w, q, r, acc);

  float d2B = 0.f, n2B = 0.f;
#pragma unroll
  for (int j = 0; j < 4; ++j) {
    const unsigned short* us = (const unsigned short*)&u0c[j];
    const unsigned short* hs = (const unsigned short*)&sv[j];
    alignas(16) unsigned short up[8];
#pragma unroll
    for (int i = 0; i < 2; ++i)
#pragma unroll
      for (int d = 0; d < 4; ++d) {
        float uo = h2f(hs[i * 4 + d]);
        float un = 0.5f * uo + 0.5f * (h2f(us[i * 4 + d]) - acc[i][j][d]);
        float df = un - uo;
        d2B += df * df;
        n2B += un * un;
        up[i * 4 + d] = f2h(un);
      }
    *(int4*)(uB + base + j * 4096) = *(const int4*)up;
  }

#pragma unroll
  for (int off = 32; off; off >>= 1) {
    d2A += __shfl_down(d2A, off, 64);
    n2A += __shfl_down(n2A, off, 64);
    d2B += __shfl_down(d2B, off, 64);
    n2B += __shfl_down(n2B, off, 64);
  }
  if (lane == 0) {
    red[w] = d2A; red[8 + w] = n2A; red[16 + w] = d2B; red[24 + w] = n2B;
  }
  __syncthreads();
  if (t == 0) {
    float a0 = 0.f, a1 = 0.f, a2 = 0.f, a3 = 0.f;
#pragma unroll
    for (int s = 0; s < 8; ++s) {
      a0 += red[s]; a1 += red[8 + s]; a2 += red[16 + s]; a3 += red[24 + s];
    }
    const int slot = blockIdx.x & 7;
    atomicAdd(&norms[itA * 16 + slot], a0);
    atomicAdd(&norms[itA * 16 + 8 + slot], a1);
    atomicAdd(&norms[(itA + 1) * 16 + slot], a2);
    atomicAdd(&norms[(itA + 1) * 16 + 8 + slot], a3);
  }
}

template <int FIRST>
__global__ __launch_bounds__(512, 4) void iter_one(
    const unsigned short* __restrict__ wrec_sw,
    const unsigned short* __restrict__ u0, const float* __restrict__ thr,
    const unsigned short* __restrict__ uin, unsigned short* __restrict__ uout,
    float* __restrict__ norms, int* __restrict__ flag, int it) {
  __shared__ short a_lds[64 * LDA];
  __shared__ float red[16];

  const int t = threadIdx.x;
  if (!FIRST) {
    if (*(volatile int*)flag) return;
    float dA = 0.f, nA = 0.f, dB = 0.f, nB = 0.f;
#pragma unroll
    for (int s = 0; s < 8; ++s) {
      dA += norms[(it - 2) * 16 + s];
      nA += norms[(it - 2) * 16 + 8 + s];
      dB += norms[(it - 1) * 16 + s];
      nB += norms[(it - 1) * 16 + 8 + s];
    }
    if (dA < 1e-6f * nA || dB < 1e-6f * nB) {
      if (t == 0) *flag = 1;
      return;
    }
  }

  const int lane = t & 63, w = t >> 6;
  const int q = lane >> 4, r = lane & 15;
  const unsigned base = blockIdx.x * 16384 + t * 8;

  float thc[2][4];
#pragma unroll
  for (int i = 0; i < 2; ++i) {
    float4 th = *(const float4*)(thr + w * 32 + i * 16 + q * 4);
    thc[i][0] = th.x; thc[i][1] = th.y; thc[i][2] = th.z; thc[i][3] = th.w;
  }

  int4 sv[4], u0c[4];
#pragma unroll
  for (int j = 0; j < 4; ++j) {
    u0c[j] = *(const int4*)(u0 + base + j * 4096);
    sv[j] = FIRST ? u0c[j] : *(const int4*)(uin + base + j * 4096);
  }

#pragma unroll
  for (int j = 0; j < 4; ++j) {
    const unsigned short* hs = (const unsigned short*)&sv[j];
#pragma unroll
    for (int i = 0; i < 2; ++i) {
      alignas(8) unsigned short ap[4];
#pragma unroll
      for (int d = 0; d < 4; ++d) {
        float a = h2f(hs[i * 4 + d]) - thc[i][d];
        ap[d] = f2bf(a > 0.f ? a : 0.f);
      }
      *(uint2*)(&a_lds[(j * 16 + r) * LDA + w * 32 + i * 16 + q * 4]) =
          *(const uint2*)ap;
    }
  }
  __syncthreads();

  f32x4 acc[2][4];
  gemm_acc8(a_lds, wrec_sw, w, q, r, acc);

  float d2 = 0.f, n2 = 0.f;
#pragma unroll
  for (int j = 0; j < 4; ++j) {
    const unsigned short* us = (const unsigned short*)&u0c[j];
    const unsigned short* hs = (const unsigned short*)&sv[j];
    alignas(16) unsigned short up[8];
#pragma unroll
    for (int i = 0; i < 2; ++i)
#pragma unroll
      for (int d = 0; d < 4; ++d) {
        float uo = FIRST ? 0.f : h2f(hs[i * 4 + d]);
        float un = 0.5f * uo + 0.5f * (h2f(us[i * 4 + d]) - acc[i][j][d]);
        float df = un - uo;
        d2 += df * df;
        n2 += un * un;
        up[i * 4 + d] = f2h(un);
      }
    *(int4*)(uout + base + j * 4096) = *(const int4*)up;
  }

#pragma unroll
  for (int off = 32; off; off >>= 1) {
    d2 += __shfl_down(d2, off, 64);
    n2 += __shfl_down(n2, off, 64);
  }
  if (lane == 0) { red[w] = d2; red[8 + w] = n2; }
  __syncthreads();
  if (t == 0) {
    float a0 = 0.f, a1 = 0.f;
#pragma unroll
    for (int s = 0; s < 8; ++s) { a0 += red[s]; a1 += red[8 + s]; }
    const int slot = blockIdx.x & 7;
    atomicAdd(&norms[it * 16 + slot], a0);
    atomicAdd(&norms[it * 16 + 8 + slot], a1);
  }
}

__global__ void sel_kernel(const float* __restrict__ norms,
                           int* __restrict__ sel) {
  int it = 1;
  for (; it <= 41; ++it) {
    float d = 0.f, n = 0.f;
    for (int s = 0; s < 8; ++s) {
      d += norms[it * 16 + s];
      n += norms[it * 16 + 8 + s];
    }
    if (d < 1e-6f * n) break;
  }
  if (it > 41) it = 41;
  *sel = (it & 1) ? 0 : 1;
}
__global__ void set_sel(int* __restrict__ sel, int v) { *sel = v; }

__global__ __launch_bounds__(512) void final_out(
    const unsigned short* __restrict__ uA,
    const unsigned short* __restrict__ uB, const int* __restrict__ sel,
    const float* __restrict__ thr, float* __restrict__ out) {
  const unsigned short* u = (*sel) ? uB : uA;
  const int t = threadIdx.x;
  const int lane = t & 63, w = t >> 6;
  const int q = lane >> 4, r = lane & 15;
  const unsigned base = blockIdx.x * 16384 + t * 8;

  float thc[2][4];
#pragma unroll
  for (int i = 0; i < 2; ++i) {
    float4 th = *(const float4*)(thr + w * 32 + i * 16 + q * 4);
    thc[i][0] = th.x; thc[i][1] = th.y; thc[i][2] = th.z; thc[i][3] = th.w;
  }

#pragma unroll
  for (int j = 0; j < 4; ++j) {
    int4 raw = *(const int4*)(u + base + j * 4096);
    const unsigned short* rs = (const unsigned short*)&raw;
    const int n = blockIdx.x * 64 + j * 16 + r;
    const int b = n / 3600, s = n - b * 3600;
    float* ob = out + (long)b * 921600 + s;
#pragma unroll
    for (int i = 0; i < 2; ++i)
#pragma unroll
      for (int d = 0; d < 4; ++d) {
        const int oc = w * 32 + i * 16 + q * 4 + d;
        float v = h2f(rs[i * 4 + d]) - thc[i][d];
        ob[oc * 3600] = v > 0.f ? v : 0.f;
      }
  }
}

// ---------------------------------------------------------------------------
extern "C" void kernel_launch(void* const* d_in, const int* in_sizes, int n_in,
                              void* d_out, int out_size, void* d_ws,
                              size_t ws_size, hipStream_t stream) {
  const float* x      = (const float*)d_in[0];
  const float* wff_f  = (const float*)d_in[1];
  const float* wrec_f = (const float*)d_in[2];
  const float* thr    = (const float*)d_in[3];
  float* out = (float*)d_out;

  char* ws = (char*)d_ws;
  int* flag = (int*)ws;                                      // [0,4)
  int* sel  = (int*)(ws + 8);                                // [8,12)
  float* norms = (float*)(ws + 64);                          // 42*16*4 = 2688 B
  unsigned short* wff     = (unsigned short*)(ws + 4096);      // 819200 B
  unsigned short* wrec_sw = (unsigned short*)(ws + 823296);    // 131072 B
  // xt (16.8 MB) aliases the head of uB (59 MB): xt dies after conv; uB is
  // only used by the fallback path.
  unsigned short* xt = (unsigned short*)(ws + 983040);
  unsigned short* uB = (unsigned short*)(ws + 983040);         // 58982400 B
  unsigned short* u0 = (unsigned short*)(ws + 59965440);       // 58982400 B
  unsigned short* uA = (unsigned short*)(ws + 118947840);      // 58982400 B
  const size_t NEEDED = 118947840ULL + 58982400ULL;            // ~178 MB

  hipMemsetAsync(d_ws, 0, 4096, stream);  // flag + sel + norm slots
  cast_weights<<<1856, 256, 0, stream>>>(wff_f, wrec_f, wff, wrec_sw);
  transpose_x<<<512, 256, 0, stream>>>(x, xt);
  conv_kernel<<<dim3(900, 2), 256, 0, stream>>>(xt, wff, u0);

  // primary: persistent cooperative iteration + fused output (1 launch)
  const unsigned short* p_wrec = wrec_sw;
  const unsigned short* p_u0 = u0;
  const float* p_thr = thr;
  float* p_norms = norms;
  float* p_out = out;
  void* cargs[] = {(void*)&p_wrec, (void*)&p_u0, (void*)&p_thr,
                   (void*)&p_norms, (void*)&p_out};
  hipError_t rc = hipLaunchCooperativeKernel(
      (const void*)iter_persist, dim3(450), dim3(512), cargs, 0, stream);

  if (rc != hipSuccess) {
    if (ws_size >= NEEDED) {
      iter_pair<1><<<1800, 512, 0, stream>>>(wrec_sw, u0, thr, uB, uA, uB,
                                             norms, flag, 1);
      for (int itA = 3; itA <= 39; itA += 2)
        iter_pair<0><<<1800, 512, 0, stream>>>(wrec_sw, u0, thr, uB, uA, uB,
                                               norms, flag, itA);
      iter_one<0><<<1800, 512, 0, stream>>>(wrec_sw, u0, thr, uB, uA, norms,
                                            flag, 41);
      sel_kernel<<<1, 1, 0, stream>>>(norms, sel);
    } else {
      iter_one<1><<<1800, 512, 0, stream>>>(wrec_sw, u0, thr, uB, uB, norms,
                                            flag, 1);
      for (int it = 2; it <= 41; ++it)
        iter_one<0><<<1800, 512, 0, stream>>>(wrec_sw, u0, thr, uB, uB, norms,
                                              flag, it);
      set_sel<<<1, 1, 0, stream>>>(sel, 1);
    }
    final_out<<<1800, 512, 0, stream>>>(uA, uB, sel, thr, out);
  }
}

// Round 8
// 991.118 us; speedup vs baseline: 3.0137x; 3.0137x over previous
//
#include <hip/hip_runtime.h>

// ---------------------------------------------------------------------------
// SparsePoolingLayer: u0 = conv5x5_valid(x, W_ff); iterate
//   u <- 0.5*u + 0.5*(u0 - W_rec @ a); a = relu(u - thr)
// until ||u_new - u||/||u_new|| < 1e-3 (device-checked), max 41 iterations.
//
// R17 design: quad-iteration launches (NO cooperative anything).
//  - R15/R16 post-mortem: cooperative persistent attempts: R9 spill, R14
//    spill + no convergence, R15 container died (infra vs hang unresolved).
//    Cooperative abandoned; multi-launch only.
//  - R17: 4 fixed-point steps per launch. sv[4]+u0c[4] regs carried across
//    all 4 steps (same budget as the proven pair kernel). Per-iteration
//    traffic 88.5 MB (was 118); launches 21 -> 12. Each step writes its
//    state to parity buffer u_(it-1)&3 -> exact first-crossing semantics.
//    final_sel fuses the norms scan + buffer select + NCHW output.
//  - FL layout (R13) everywhere: thread t accesses int4 at
//    tile*16384 + j*4096 + t*8; fully coalesced, no L2 partial-line thrash.
//  - ws gating: quad path needs ~296 MB; falls back to proven pair path
//    (~178 MB, R13 = 1075 us), then single-chain.
// ---------------------------------------------------------------------------

typedef __attribute__((ext_vector_type(8))) short short8;
typedef __attribute__((ext_vector_type(4))) float f32x4;

#define NTOT 115200   // 32*60*60
#define CHW  262144   // 64*64*64
#define HW2  4096     // 64*64
#define LDA  264      // a_lds row stride in shorts (528 B)
#define LDC  40       // conv LDS row stride in shorts (80 B, 16B-aligned rows)

__device__ __forceinline__ unsigned short f2bf(float f) {
  unsigned int u = __float_as_uint(f);
  unsigned int r = u + 0x7FFFu + ((u >> 16) & 1u);
  return (unsigned short)(r >> 16);
}
__device__ __forceinline__ float bf2f(unsigned short h) {
  return __uint_as_float(((unsigned int)h) << 16);
}
__device__ __forceinline__ unsigned short f2h(float f) {
  _Float16 x = (_Float16)f;
  unsigned short r;
  __builtin_memcpy(&r, &x, 2);
  return r;
}
__device__ __forceinline__ float h2f(unsigned short h) {
  _Float16 x;
  __builtin_memcpy(&x, &h, 2);
  return (float)x;
}

// ---------------------------------------------------------------------------
// Weight prep (unchanged).
__global__ void cast_weights(const float* __restrict__ wff_f,
                             const float* __restrict__ wrec_f,
                             unsigned short* __restrict__ wff,
                             unsigned short* __restrict__ wrec_sw) {
  int tid = blockIdx.x * 256 + threadIdx.x;
  if (tid < 409600) {
    int o = tid / 1600, k = tid % 1600;
    int kk = k >> 6, ci = k & 63;            // k = kk*64 + ci
    wff[tid] = f2bf(wff_f[o * 1600 + ci * 25 + kk]);
  } else if (tid < 409600 + 65536) {
    int i = tid - 409600;
    int o = i >> 8, ic = i & 255;
    wrec_sw[(((ic >> 3) << 8) + o) * 8 + (ic & 7)] = f2bf(wrec_f[i]);
  }
}

// ---------------------------------------------------------------------------
// x NCHW fp32 -> NHWC bf16 (unchanged).
__global__ __launch_bounds__(256) void transpose_x(
    const float* __restrict__ x, unsigned short* __restrict__ xt) {
  int g = blockIdx.x * 256 + threadIdx.x;          // 131072 = 32*4096
  const float* src = x + (long)(g >> 12) * CHW + (g & 4095);
  unsigned short* dst = xt + (long)g * 64;
#pragma unroll
  for (int oct = 0; oct < 8; ++oct) {
    alignas(16) unsigned short tmp[8];
#pragma unroll
    for (int d = 0; d < 8; ++d)
      tmp[d] = f2bf(src[(oct * 8 + d) * HW2]);
    *(int4*)(dst + oct * 8) = *(const int4*)tmp;
  }
}

// ---------------------------------------------------------------------------
// Conv as implicit GEMM (unchanged R13; FL-layout u0 output).
__global__ __launch_bounds__(256) void conv_kernel(
    const unsigned short* __restrict__ xt,
    const unsigned short* __restrict__ wff,
    unsigned short* __restrict__ u0_fl) {
  __shared__ short As[128 * LDC];  // x-tile  [n][k]  pad 32->40
  __shared__ short Bs[128 * LDC];  // wff     [oc][k]
  const int t = threadIdx.x;
  const int n0 = blockIdx.x * 128;
  const int oc0 = blockIdx.y * 128;
  const int lane = t & 63, w = t >> 6;
  const int q = lane >> 4, r = lane & 15;
  const int woc = w >> 1, wn = w & 1;      // oc-half, n-half
  const int qt = t & 3, mrow = t >> 2;     // staging: row mrow(+64), 16B qt

  int xbase[2];
#pragma unroll
  for (int p = 0; p < 2; ++p) {
    int n = n0 + p * 64 + mrow;
    int bb = n / 3600, rem = n - bb * 3600;
    int yy = rem / 60, xx = rem - yy * 60;
    xbase[p] = (bb * 4096 + yy * 64 + xx) * 64 + qt * 8;
  }

  f32x4 acc[4][4];
#pragma unroll
  for (int i = 0; i < 4; i++)
#pragma unroll
    for (int j = 0; j < 4; j++) acc[i][j] = (f32x4){0.f, 0.f, 0.f, 0.f};

  for (int c = 0; c < 50; ++c) {
    const int k0 = c * 32;
    const int kk = c >> 1;                 // ky*5+kx, uniform per chunk
    const int ky = kk / 5, kx = kk - ky * 5;
    const int choff = (ky * 64 + kx) * 64 + (c & 1) * 32;  // scalar-uniform

    __syncthreads();
#pragma unroll
    for (int p = 0; p < 2; ++p) {          // wff: 128 oc-rows x 32 k
      int m = p * 64 + mrow;
      *(int4*)(&Bs[m * LDC + qt * 8]) =
          *(const int4*)(wff + (oc0 + m) * 1600 + k0 + qt * 8);
    }
#pragma unroll
    for (int p = 0; p < 2; ++p) {          // x-tile: contiguous bf16 (NHWC)
      int m = p * 64 + mrow;
      *(int4*)(&As[m * LDC + qt * 8]) = *(const int4*)(xt + xbase[p] + choff);
    }
    __syncthreads();

    short8 xf[4], wf[4];
#pragma unroll
    for (int j = 0; j < 4; j++)
      xf[j] = *(const short8*)(&As[(wn * 64 + j * 16 + r) * LDC + q * 8]);
#pragma unroll
    for (int i = 0; i < 4; i++)
      wf[i] = *(const short8*)(&Bs[(woc * 64 + i * 16 + r) * LDC + q * 8]);
#pragma unroll
    for (int i = 0; i < 4; i++)
#pragma unroll
      for (int j = 0; j < 4; j++)
        acc[i][j] = __builtin_amdgcn_mfma_f32_16x16x32_bf16(wf[i], xf[j],
                                                            acc[i][j], 0, 0, 0);
  }

  // epilogue: FL layout, lane-contiguous coalesced int4 stores.
  const int tile = blockIdx.x * 2 + wn;
#pragma unroll
  for (int j = 0; j < 4; j++) {
#pragma unroll
    for (int p = 0; p < 2; p++) {
      const int w_fl = blockIdx.y * 4 + woc * 2 + p;
      alignas(16) unsigned short up[8];
#pragma unroll
      for (int d = 0; d < 4; ++d) up[d] = f2h(acc[2 * p][j][d]);
#pragma unroll
      for (int d = 0; d < 4; ++d) up[4 + d] = f2h(acc[2 * p + 1][j][d]);
      *(int4*)(&u0_fl[tile * 16384 + j * 4096 + (w_fl * 64 + q * 16 + r) * 8]) =
          *(const int4*)up;
    }
  }
}

// ---------------------------------------------------------------------------
// 8-wave GEMM accumulate: acc = W_rec @ a, C-layout. Wave w owns oc rows
// [32w, 32w+32). No LDS writeback, no barriers (caller manages).
__device__ __forceinline__ void gemm_acc8(const short* a_lds,
                                          const unsigned short* __restrict__
                                              wrec_sw,
                                          int w, int q, int r,
                                          f32x4 acc[2][4]) {
#pragma unroll
  for (int i = 0; i < 2; i++)
#pragma unroll
    for (int j = 0; j < 4; j++) acc[i][j] = (f32x4){0.f, 0.f, 0.f, 0.f};

#pragma unroll
  for (int c = 0; c < 8; ++c) {
    short8 afr[2], bfr[4];
#pragma unroll
    for (int i = 0; i < 2; i++)
      afr[i] = *(const short8*)(wrec_sw +
               (((c * 4 + q) << 8) + w * 32 + i * 16 + r) * 8);
#pragma unroll
    for (int j = 0; j < 4; j++)
      bfr[j] = *(const short8*)(&a_lds[(j * 16 + r) * LDA + c * 32 + q * 8]);
#pragma unroll
    for (int i = 0; i < 2; i++)
#pragma unroll
      for (int j = 0; j < 4; j++)
        acc[i][j] = __builtin_amdgcn_mfma_f32_16x16x32_bf16(afr[i], bfr[j],
                                                            acc[i][j], 0, 0, 0);
  }
}

// ---------------------------------------------------------------------------
// Quad iteration: computes iterations it1..it1+3 per launch (it1 odd, 1 mod 4).
// 512 threads / 8 waves, grid 1800 (64 n each). sv/u0c carried in regs
// across all 4 steps; step it writes its state to parity buffer (it-1)&3
// (o1..o4) -> first-crossing state always preserved.
template <int FIRST>
__global__ __launch_bounds__(512, 4) void iter_quad(
    const unsigned short* __restrict__ wrec_sw,
    const unsigned short* __restrict__ u0, const float* __restrict__ thr,
    const unsigned short* __restrict__ uin,      // u_{it1-1} (prev o4)
    unsigned short* __restrict__ o1, unsigned short* __restrict__ o2,
    unsigned short* __restrict__ o3, unsigned short* __restrict__ o4,
    float* __restrict__ norms, int* __restrict__ flag, int it1) {
  __shared__ short a_lds[64 * LDA];
  __shared__ float red[64];

  const int t = threadIdx.x;
  if (!FIRST) {
    if (*(volatile int*)flag) return;            // converged earlier
    bool hit = false;                            // any of prev quad's 4 rows?
#pragma unroll
    for (int rr = 0; rr < 4; ++rr) {
      float d = 0.f, n = 0.f;
#pragma unroll
      for (int s = 0; s < 8; ++s) {
        d += norms[(it1 - 4 + rr) * 16 + s];
        n += norms[(it1 - 4 + rr) * 16 + 8 + s];
      }
      hit = hit || (d < 1e-6f * n);              // fro ratio < 1e-3
    }
    if (hit) {
      if (t == 0) *flag = 1;
      return;
    }
  }

  const int lane = t & 63, w = t >> 6;     // w in 0..7
  const int q = lane >> 4, r = lane & 15;
  const unsigned base = blockIdx.x * 16384 + t * 8;   // + j*4096

  float thc[2][4];
#pragma unroll
  for (int i = 0; i < 2; ++i) {
    float4 th = *(const float4*)(thr + w * 32 + i * 16 + q * 4);
    thc[i][0] = th.x; thc[i][1] = th.y; thc[i][2] = th.z; thc[i][3] = th.w;
  }

  int4 sv[4], u0c[4];                      // j-indexed, 8 fp16 each
#pragma unroll
  for (int j = 0; j < 4; ++j) {
    u0c[j] = *(const int4*)(u0 + base + j * 4096);
    sv[j] = FIRST ? u0c[j] : *(const int4*)(uin + base + j * 4096);
  }

  float d2[4], n2[4];
#pragma unroll
  for (int p = 0; p < 4; ++p) { d2[p] = 0.f; n2[p] = 0.f; }

  // One fixed-point step: stage a from sv -> LDS; GEMM; in-reg update; store
  // state to OUT. Two barriers: pre-GEMM (a visible) + post-update (all GEMM
  // a_lds reads complete before next phase restages).
#define QPHASE(PH, OUT)                                                       \
  {                                                                           \
    _Pragma("unroll")                                                         \
    for (int j = 0; j < 4; ++j) {                                             \
      const unsigned short* hs = (const unsigned short*)&sv[j];               \
      _Pragma("unroll")                                                       \
      for (int i = 0; i < 2; ++i) {                                           \
        alignas(8) unsigned short ap[4];                                      \
        _Pragma("unroll")                                                     \
        for (int d = 0; d < 4; ++d) {                                         \
          float a = h2f(hs[i * 4 + d]) - thc[i][d];                           \
          ap[d] = f2bf(a > 0.f ? a : 0.f);                                    \
        }                                                                     \
        *(uint2*)(&a_lds[(j * 16 + r) * LDA + w * 32 + i * 16 + q * 4]) =     \
            *(const uint2*)ap;                                                \
      }                                                                       \
    }                                                                         \
    __syncthreads();                                                          \
    f32x4 acc[2][4];                                                          \
    gemm_acc8(a_lds, wrec_sw, w, q, r, acc);                                  \
    _Pragma("unroll")                                                         \
    for (int j = 0; j < 4; ++j) {                                             \
      const unsigned short* us = (const unsigned short*)&u0c[j];              \
      const unsigned short* hs = (const unsigned short*)&sv[j];               \
      alignas(16) unsigned short up[8];                                       \
      _Pragma("unroll")                                                       \
      for (int i = 0; i < 2; ++i)                                             \
        _Pragma("unroll")                                                     \
        for (int d = 0; d < 4; ++d) {                                         \
          float uo = (FIRST && (PH) == 1) ? 0.f : h2f(hs[i * 4 + d]);         \
          float un = 0.5f * uo + 0.5f * (h2f(us[i * 4 + d]) - acc[i][j][d]);  \
          float df = un - uo;                                                 \
          d2[(PH)-1] += df * df;                                              \
          n2[(PH)-1] += un * un;                                              \
          up[i * 4 + d] = f2h(un);                                            \
        }                                                                     \
      sv[j] = *(const int4*)up;                                               \
      *(int4*)((OUT) + base + j * 4096) = sv[j];                              \
    }                                                                         \
    __syncthreads();                                                          \
  }

  QPHASE(1, o1)
  QPHASE(2, o2)
  QPHASE(3, o3)
  QPHASE(4, o4)
#undef QPHASE

  // ---- reduce: wave -> block -> 8-slot atomics, 4 iteration rows ----
#pragma unroll
  for (int off = 32; off; off >>= 1)
#pragma unroll
    for (int p = 0; p < 4; ++p) {
      d2[p] += __shfl_down(d2[p], off, 64);
      n2[p] += __shfl_down(n2[p], off, 64);
    }
  if (lane == 0)
#pragma unroll
    for (int p = 0; p < 4; ++p) {
      red[p * 16 + w] = d2[p];
      red[p * 16 + 8 + w] = n2[p];
    }
  __syncthreads();
  if (t == 0) {
    const int slot = blockIdx.x & 7;
#pragma unroll
    for (int p = 0; p < 4; ++p) {
      float a0 = 0.f, a1 = 0.f;
#pragma unroll
      for (int s = 0; s < 8; ++s) {
        a0 += red[p * 16 + s];
        a1 += red[p * 16 + 8 + s];
      }
      atomicAdd(&norms[(it1 + p) * 16 + slot], a0);
      atomicAdd(&norms[(it1 + p) * 16 + 8 + slot], a1);
    }
  }
}

// ---------------------------------------------------------------------------
// Pair iteration (R13 proven, fallback path). Writes uA (odd), uB (even).
template <int FIRST>
__global__ __launch_bounds__(512, 4) void iter_pair(
    const unsigned short* __restrict__ wrec_sw,
    const unsigned short* __restrict__ u0, const float* __restrict__ thr,
    const unsigned short* __restrict__ uin,
    unsigned short* __restrict__ uA, unsigned short* __restrict__ uB,
    float* __restrict__ norms, int* __restrict__ flag, int itA) {
  __shared__ short a_lds[64 * LDA];
  __shared__ float red[32];

  const int t = threadIdx.x;
  if (!FIRST) {
    if (*(volatile int*)flag) return;
    float dA = 0.f, nA = 0.f, dB = 0.f, nB = 0.f;
#pragma unroll
    for (int s = 0; s < 8; ++s) {
      dA += norms[(itA - 2) * 16 + s];
      nA += norms[(itA - 2) * 16 + 8 + s];
      dB += norms[(itA - 1) * 16 + s];
      nB += norms[(itA - 1) * 16 + 8 + s];
    }
    if (dA < 1e-6f * nA || dB < 1e-6f * nB) {
      if (t == 0) *flag = 1;
      return;
    }
  }

  const int lane = t & 63, w = t >> 6;
  const int q = lane >> 4, r = lane & 15;
  const unsigned base = blockIdx.x * 16384 + t * 8;

  float thc[2][4];
#pragma unroll
  for (int i = 0; i < 2; ++i) {
    float4 th = *(const float4*)(thr + w * 32 + i * 16 + q * 4);
    thc[i][0] = th.x; thc[i][1] = th.y; thc[i][2] = th.z; thc[i][3] = th.w;
  }

  int4 sv[4], u0c[4];
#pragma unroll
  for (int j = 0; j < 4; ++j) {
    u0c[j] = *(const int4*)(u0 + base + j * 4096);
    sv[j] = FIRST ? u0c[j] : *(const int4*)(uin + base + j * 4096);
  }

#pragma unroll
  for (int j = 0; j < 4; ++j) {
    const unsigned short* hs = (const unsigned short*)&sv[j];
#pragma unroll
    for (int i = 0; i < 2; ++i) {
      alignas(8) unsigned short ap[4];
#pragma unroll
      for (int d = 0; d < 4; ++d) {
        float a = h2f(hs[i * 4 + d]) - thc[i][d];
        ap[d] = f2bf(a > 0.f ? a : 0.f);
      }
      *(uint2*)(&a_lds[(j * 16 + r) * LDA + w * 32 + i * 16 + q * 4]) =
          *(const uint2*)ap;
    }
  }
  __syncthreads();

  f32x4 acc[2][4];
  gemm_acc8(a_lds, wrec_sw, w, q, r, acc);

  float d2A = 0.f, n2A = 0.f;
#pragma unroll
  for (int j = 0; j < 4; ++j) {
    const unsigned short* us = (const unsigned short*)&u0c[j];
    const unsigned short* hs = (const unsigned short*)&sv[j];
    alignas(16) unsigned short up[8];
#pragma unroll
    for (int i = 0; i < 2; ++i)
#pragma unroll
      for (int d = 0; d < 4; ++d) {
        float uo = FIRST ? 0.f : h2f(hs[i * 4 + d]);
        float un = 0.5f * uo + 0.5f * (h2f(us[i * 4 + d]) - acc[i][j][d]);
        float df = un - uo;
        d2A += df * df;
        n2A += un * un;
        up[i * 4 + d] = f2h(un);
      }
    sv[j] = *(const int4*)up;
    *(int4*)(uA + base + j * 4096) = sv[j];
  }
  __syncthreads();

#pragma unroll
  for (int j = 0; j < 4; ++j) {
    const unsigned short* hs = (const unsigned short*)&sv[j];
#pragma unroll
    for (int i = 0; i < 2; ++i) {
      alignas(8) unsigned short ap[4];
#pragma unroll
      for (int d = 0; d < 4; ++d) {
        float a = h2f(hs[i * 4 + d]) - thc[i][d];
        ap[d] = f2bf(a > 0.f ? a : 0.f);
      }
      *(uint2*)(&a_lds[(j * 16 + r) * LDA + w * 32 + i * 16 + q * 4]) =
          *(const uint2*)ap;
    }
  }
  __syncthreads();

  gemm_acc8(a_lds, wrec_sw, w, q, r, acc);

  float d2B = 0.f, n2B = 0.f;
#pragma unroll
  for (int j = 0; j < 4; ++j) {
    const unsigned short* us = (const unsigned short*)&u0c[j];
    const unsigned short* hs = (const unsigned short*)&sv[j];
    alignas(16) unsigned short up[8];
#pragma unroll
    for (int i = 0; i < 2; ++i)
#pragma unroll
      for (int d = 0; d < 4; ++d) {
        float uo = h2f(hs[i * 4 + d]);
        float un = 0.5f * uo + 0.5f * (h2f(us[i * 4 + d]) - acc[i][j][d]);
        float df = un - uo;
        d2B += df * df;
        n2B += un * un;
        up[i * 4 + d] = f2h(un);
      }
    *(int4*)(uB + base + j * 4096) = *(const int4*)up;
  }

#pragma unroll
  for (int off = 32; off; off >>= 1) {
    d2A += __shfl_down(d2A, off, 64);
    n2A += __shfl_down(n2A, off, 64);
    d2B += __shfl_down(d2B, off, 64);
    n2B += __shfl_down(n2B, off, 64);
  }
  if (lane == 0) {
    red[w] = d2A; red[8 + w] = n2A; red[16 + w] = d2B; red[24 + w] = n2B;
  }
  __syncthreads();
  if (t == 0) {
    float a0 = 0.f, a1 = 0.f, a2 = 0.f, a3 = 0.f;
#pragma unroll
    for (int s = 0; s < 8; ++s) {
      a0 += red[s]; a1 += red[8 + s]; a2 += red[16 + s]; a3 += red[24 + s];
    }
    const int slot = blockIdx.x & 7;
    atomicAdd(&norms[itA * 16 + slot], a0);
    atomicAdd(&norms[itA * 16 + 8 + slot], a1);
    atomicAdd(&norms[(itA + 1) * 16 + slot], a2);
    atomicAdd(&norms[(itA + 1) * 16 + 8 + slot], a3);
  }
}

// ---------------------------------------------------------------------------
// Single iteration it: uin -> uout. ROWS = how many predecessor rows the
// stub-check covers (2 after a pair, 4 after a quad; 0 unused for FIRST).
template <int FIRST, int ROWS>
__global__ __launch_bounds__(512, 4) void iter_one(
    const unsigned short* __restrict__ wrec_sw,
    const unsigned short* __restrict__ u0, const float* __restrict__ thr,
    const unsigned short* __restrict__ uin, unsigned short* __restrict__ uout,
    float* __restrict__ norms, int* __restrict__ flag, int it) {
  __shared__ short a_lds[64 * LDA];
  __shared__ float red[16];

  const int t = threadIdx.x;
  if (!FIRST) {
    if (*(volatile int*)flag) return;
    bool hit = false;
#pragma unroll
    for (int rr = 0; rr < ROWS; ++rr) {
      float d = 0.f, n = 0.f;
#pragma unroll
      for (int s = 0; s < 8; ++s) {
        d += norms[(it - ROWS + rr) * 16 + s];
        n += norms[(it - ROWS + rr) * 16 + 8 + s];
      }
      hit = hit || (d < 1e-6f * n);
    }
    if (hit) {
      if (t == 0) *flag = 1;
      return;
    }
  }

  const int lane = t & 63, w = t >> 6;
  const int q = lane >> 4, r = lane & 15;
  const unsigned base = blockIdx.x * 16384 + t * 8;

  float thc[2][4];
#pragma unroll
  for (int i = 0; i < 2; ++i) {
    float4 th = *(const float4*)(thr + w * 32 + i * 16 + q * 4);
    thc[i][0] = th.x; thc[i][1] = th.y; thc[i][2] = th.z; thc[i][3] = th.w;
  }

  int4 sv[4], u0c[4];
#pragma unroll
  for (int j = 0; j < 4; ++j) {
    u0c[j] = *(const int4*)(u0 + base + j * 4096);
    sv[j] = FIRST ? u0c[j] : *(const int4*)(uin + base + j * 4096);
  }

#pragma unroll
  for (int j = 0; j < 4; ++j) {
    const unsigned short* hs = (const unsigned short*)&sv[j];
#pragma unroll
    for (int i = 0; i < 2; ++i) {
      alignas(8) unsigned short ap[4];
#pragma unroll
      for (int d = 0; d < 4; ++d) {
        float a = h2f(hs[i * 4 + d]) - thc[i][d];
        ap[d] = f2bf(a > 0.f ? a : 0.f);
      }
      *(uint2*)(&a_lds[(j * 16 + r) * LDA + w * 32 + i * 16 + q * 4]) =
          *(const uint2*)ap;
    }
  }
  __syncthreads();

  f32x4 acc[2][4];
  gemm_acc8(a_lds, wrec_sw, w, q, r, acc);

  float d2 = 0.f, n2 = 0.f;
#pragma unroll
  for (int j = 0; j < 4; ++j) {
    const unsigned short* us = (const unsigned short*)&u0c[j];
    const unsigned short* hs = (const unsigned short*)&sv[j];
    alignas(16) unsigned short up[8];
#pragma unroll
    for (int i = 0; i < 2; ++i)
#pragma unroll
      for (int d = 0; d < 4; ++d) {
        float uo = FIRST ? 0.f : h2f(hs[i * 4 + d]);
        float un = 0.5f * uo + 0.5f * (h2f(us[i * 4 + d]) - acc[i][j][d]);
        float df = un - uo;
        d2 += df * df;
        n2 += un * un;
        up[i * 4 + d] = f2h(un);
      }
    *(int4*)(uout + base + j * 4096) = *(const int4*)up;
  }

#pragma unroll
  for (int off = 32; off; off >>= 1) {
    d2 += __shfl_down(d2, off, 64);
    n2 += __shfl_down(n2, off, 64);
  }
  if (lane == 0) { red[w] = d2; red[8 + w] = n2; }
  __syncthreads();
  if (t == 0) {
    float a0 = 0.f, a1 = 0.f;
#pragma unroll
    for (int s = 0; s < 8; ++s) { a0 += red[s]; a1 += red[8 + s]; }
    const int slot = blockIdx.x & 7;
    atomicAdd(&norms[it * 16 + slot], a0);
    atomicAdd(&norms[it * 16 + 8 + slot], a1);
  }
}

// ---------------------------------------------------------------------------
// Fused sel + output: scan norms for first crossing it* (else 41); buffer =
// parity slot (it*-1)&3 of (b0,b1,b2,b3); out(NCHW fp32) = relu(u - thr).
// Pair path passes (uA,uB,uA,uB); single-chain passes (uB,uB,uB,uB).
__global__ __launch_bounds__(512) void final_sel(
    const unsigned short* __restrict__ b0, const unsigned short* __restrict__ b1,
    const unsigned short* __restrict__ b2, const unsigned short* __restrict__ b3,
    const float* __restrict__ norms, const float* __restrict__ thr,
    float* __restrict__ out) {
  int it = 1;
  for (; it <= 41; ++it) {
    float d = 0.f, n = 0.f;
    for (int s = 0; s < 8; ++s) {
      d += norms[it * 16 + s];
      n += norms[it * 16 + 8 + s];
    }
    if (d < 1e-6f * n) break;
  }
  if (it > 41) it = 41;
  const int k = (it - 1) & 3;
  const unsigned short* u = (k & 2) ? ((k & 1) ? b3 : b2)
                                    : ((k & 1) ? b1 : b0);

  const int t = threadIdx.x;
  const int lane = t & 63, w = t >> 6;
  const int q = lane >> 4, r = lane & 15;
  const unsigned base = blockIdx.x * 16384 + t * 8;

  float thc[2][4];
#pragma unroll
  for (int i = 0; i < 2; ++i) {
    float4 th = *(const float4*)(thr + w * 32 + i * 16 + q * 4);
    thc[i][0] = th.x; thc[i][1] = th.y; thc[i][2] = th.z; thc[i][3] = th.w;
  }

#pragma unroll
  for (int j = 0; j < 4; ++j) {
    int4 raw = *(const int4*)(u + base + j * 4096);
    const unsigned short* rs = (const unsigned short*)&raw;
    const int n = blockIdx.x * 64 + j * 16 + r;
    const int b = n / 3600, s = n - b * 3600;
    float* ob = out + (long)b * 921600 + s;
#pragma unroll
    for (int i = 0; i < 2; ++i)
#pragma unroll
      for (int d = 0; d < 4; ++d) {
        const int oc = w * 32 + i * 16 + q * 4 + d;
        float v = h2f(rs[i * 4 + d]) - thc[i][d];
        ob[oc * 3600] = v > 0.f ? v : 0.f;
      }
  }
}

// ---------------------------------------------------------------------------
extern "C" void kernel_launch(void* const* d_in, const int* in_sizes, int n_in,
                              void* d_out, int out_size, void* d_ws,
                              size_t ws_size, hipStream_t stream) {
  const float* x      = (const float*)d_in[0];
  const float* wff_f  = (const float*)d_in[1];
  const float* wrec_f = (const float*)d_in[2];
  const float* thr    = (const float*)d_in[3];
  float* out = (float*)d_out;

  char* ws = (char*)d_ws;
  int* flag = (int*)ws;                                      // [0,4)
  float* norms = (float*)(ws + 64);                          // 42*16*4 = 2688 B
  unsigned short* wff     = (unsigned short*)(ws + 4096);      // 819200 B
  unsigned short* wrec_sw = (unsigned short*)(ws + 823296);    // 131072 B
  // xt (16.8 MB) aliases the head of uD: xt dies after conv; uD is first
  // written in phase 4 of the first quad (or pair-B of the first pair).
  unsigned short* xt = (unsigned short*)(ws + 983040);
  unsigned short* uD = (unsigned short*)(ws + 983040);         // 58982400 B
  unsigned short* u0 = (unsigned short*)(ws + 59965440);       // 58982400 B
  unsigned short* uA = (unsigned short*)(ws + 118947840);      // 58982400 B
  unsigned short* uB = (unsigned short*)(ws + 177930240);      // 58982400 B
  unsigned short* uC = (unsigned short*)(ws + 236912640);      // 58982400 B
  const size_t NEED_QUAD = 236912640ULL + 58982400ULL;         // ~296 MB
  const size_t NEED_PAIR = 118947840ULL + 58982400ULL;         // ~178 MB

  hipMemsetAsync(d_ws, 0, 4096, stream);  // flag + norm slots
  cast_weights<<<1856, 256, 0, stream>>>(wff_f, wrec_f, wff, wrec_sw);
  transpose_x<<<512, 256, 0, stream>>>(x, xt);
  conv_kernel<<<dim3(900, 2), 256, 0, stream>>>(xt, wff, u0);

  if (ws_size >= NEED_QUAD) {
    // quads (1-4), (5-8), ..., (37-40), then single 41 -> 41 bodies total
    iter_quad<1><<<1800, 512, 0, stream>>>(wrec_sw, u0, thr, uD, uA, uB, uC,
                                           uD, norms, flag, 1);
    for (int it1 = 5; it1 <= 37; it1 += 4)
      iter_quad<0><<<1800, 512, 0, stream>>>(wrec_sw, u0, thr, uD, uA, uB, uC,
                                             uD, norms, flag, it1);
    iter_one<0, 4><<<1800, 512, 0, stream>>>(wrec_sw, u0, thr, uD, uA, norms,
                                             flag, 41);   // 41 -> slot 0 = uA
    final_sel<<<1800, 512, 0, stream>>>(uA, uB, uC, uD, norms, thr, out);
  } else if (ws_size >= NEED_PAIR) {
    // proven R13 pair path: even states in uD slot, odd in uA
    iter_pair<1><<<1800, 512, 0, stream>>>(wrec_sw, u0, thr, uD, uA, uD,
                                           norms, flag, 1);
    for (int itA = 3; itA <= 39; itA += 2)
      iter_pair<0><<<1800, 512, 0, stream>>>(wrec_sw, u0, thr, uD, uA, uD,
                                             norms, flag, itA);
    iter_one<0, 2><<<1800, 512, 0, stream>>>(wrec_sw, u0, thr, uD, uA, norms,
                                             flag, 41);
    // parity map: 1->uA, 2->uD, 3->uA, 0->uD
    final_sel<<<1800, 512, 0, stream>>>(uA, uD, uA, uD, norms, thr, out);
  } else {
    // single chain in uD
    iter_one<1, 0><<<1800, 512, 0, stream>>>(wrec_sw, u0, thr, uD, uD, norms,
                                             flag, 1);
    for (int it = 2; it <= 41; ++it)
      iter_one<0, 2><<<1800, 512, 0, stream>>>(wrec_sw, u0, thr, uD, uD,
                                               norms, flag, it);
    final_sel<<<1800, 512, 0, stream>>>(uD, uD, uD, uD, norms, thr, out);
  }
}